// Round 12
// baseline (602.618 us; speedup 1.0000x reference)
//
#include <hip/hip_runtime.h>
#include <math.h>

#define NN 4096
#define STRIPS 32
#define SW 128                        // strip width (columns per workgroup)
#define RING_ROWS 256                 // power of 2: slot = row & 255
#define RINGB (RING_ROWS * SW * 4)    // 131072 B
#define BATCH 64
#define NBATCH 65                     // (NN + 64) / BATCH
#define PAD 64                        // colbuf per-strip padding rows
#define COLPITCH (NN + 2 * PAD)
#define INFV 1e30f
#define SENTU 0xFFFFFFFFu             // memset(0xFF) sentinel, never a DP result

// lane l <- lane l-1 (whole-wave shift right by 1), VALU-latency cross-lane move
__device__ __forceinline__ float dpp_wave_shr1(float x) {
    return __int_as_float(__builtin_amdgcn_update_dpp(
        0, __float_as_int(x), 0x138 /*WAVE_SHR1*/, 0xf, 0xf, false));
}

// all 64 lanes load one boundary row each (clamped): always exactly 1 vmem inst
__device__ __forceinline__ float bload(const unsigned* colL, int row) {
    const int rowc = (row < NN) ? row : (NN - 1);
    unsigned u = __hip_atomic_load(colL + rowc, __ATOMIC_RELAXED,
                                   __HIP_MEMORY_SCOPE_AGENT);
    return __uint_as_float(u);
}

// rows [rb, rb+64) still hold the memset sentinel? (rows >= NN masked off)
__device__ __forceinline__ bool has_sent(float b, int rb, int lane) {
    return __any(((rb + lane) < NN) && (__float_as_uint(b) == SENTU));
}

// async-stage rows [rb, rb+64) (128 cols) into the LDS ring at slot (row&255).
// ALWAYS exactly 32 global_load_lds (source rows clamped; slot from the
// UNCLAMPED row -- aliases only rows outside the live window).
__device__ __forceinline__ void stageB(const float* Sg, float* ring, int rb,
                                       int lane) {
    #pragma unroll
    for (int k = 0; k < 32; ++k) {
        const int r0 = rb + 2 * k;
        const int r0c = (r0 < NN - 1) ? r0 : (NN - 2);
        const int slot = r0 & (RING_ROWS - 1);
        const float* gsrc =
            Sg + (size_t)(r0c + (lane >> 5)) * NN + ((lane & 31) << 2);
        __builtin_amdgcn_global_load_lds(
            (const __attribute__((address_space(1))) unsigned*)gsrc,
            (__attribute__((address_space(3))) unsigned*)((char*)ring +
                                                         slot * (SW * 4)),
            16, 0, 0);
    }
}

// ---------------------------------------------------------------------------
// Single-wave DP: 32 workgroups x 1 wave (64 lanes), no barriers.
// Strip g owns cols [128g, 128g+128); lane l owns cols 2l, 2l+1; at step t
// lane l computes row r = t - l. Left/diag deps via DPP wave_shr1 chain.
//
// Per batch n (tb = 64n):
//   1. validate boundary regs qv = rows [tb, tb+64) (prefetched last batch;
//      steady state: one ballot, no spin). Spin reloads only ADD newer vmem
//      ops -> the counted wait below becomes stricter, never wrong.
//   2. s_waitcnt vmcnt(34|33): all ops older than the newest 34 retired.
//      Steady-state newest-34 = batch n-1's {qv(1), publish(1), stage(32)};
//      everything older includes stage(n) (issued at end of batch n-2) =>
//      rows [tb, tb+64) are in LDS. Exact with no spins, conservative with.
//   3. issue next boundary prefetch qvn = rows [tb+64, tb+128)  (1 op)
//   4. chain: 64 grouped ds_reads + 64-step register chain; lane63 writes c1
//      per step to an LDS outbox via the zero-divergence obp walk; on-the-fly
//      e = exp(-D) (exp issue fits in the latency-bound chain's idle slots)
//   5. lgkmcnt(0); all lanes read outbox[lane]; ONE agent store per lane
//      publishes rows [tb-63, tb]  (lag floor: consumer batch n needs
//      producer batch n+1's end => 2-batch pipeline lag)
//   6. stageB(tb+128) post-chain: any LDS-DMA issue stall lands in idle time,
//      flight overlaps the next batch's chain, landing proven by step 2 two
//      batches later.
// Ring span: reads [tb-63, tb+63] + staged-ahead [tb+128, tb+192) => 255-row
// window < 256. Pre-start slots [192,256) cleared to 0 (INF+exp(0)=INF ok).
// ---------------------------------------------------------------------------
__global__ __launch_bounds__(64, 1) void dtw_dp(const float* __restrict__ D,
                                                float* __restrict__ cost_out,
                                                unsigned* __restrict__ colbuf) {
    __shared__ float ring[RING_ROWS * SW];   // 128 KB
    __shared__ float outbox[BATCH];
    __shared__ float outdummy[64];

    const int lane = threadIdx.x;
    const int b = blockIdx.x;
    const int g = ((b & 7) << 2) | (b >> 3);   // XCD-affinity strip remap

    const float* Dg = D + g * SW;
    const unsigned* colL = colbuf + (size_t)(g - 1) * COLPITCH + PAD;
    unsigned* colM = colbuf + (size_t)g * COLPITCH + PAD;
    const bool lane0 = (lane == 0);
    const int ostep = (lane == 63) ? 1 : 0;

    // clear pre-start ring slots [192,256): rows r<0 read 0
    {
        const float4 z = make_float4(0.f, 0.f, 0.f, 0.f);
        float4* r4 = reinterpret_cast<float4*>(&ring[192 * SW]);
        #pragma unroll
        for (int i = 0; i < 32; ++i) r4[i * 64 + lane] = z;
    }

    // prologue: stage rows [0,128) (batches 0,1); issue boundary prefetch
    stageB(Dg, ring, 0, lane);
    stageB(Dg, ring, 64, lane);
    float qv = INFV;
    if (g > 0) qv = bload(colL, lane);            // rows [0,64), maybe sentinel
    asm volatile("s_waitcnt vmcnt(0) lgkmcnt(0)" ::: "memory");

    float cur0 = INFV, cur1 = INFV;   // my c[r-1][2l], c[r-1][2l+1]
    float l1s = INFV, l2s = INFV;     // lane l-1's c1 from t-1, t-2
    float bprevc = INFV;              // boundary carry (row tb-1)
    float save = 0.f;

    // per-lane ring byte address of (row tb-lane, col 2*lane), batch 0
    unsigned caddr = ((unsigned)((0 - lane) & (RING_ROWS - 1)) << 9) |
                     ((unsigned)lane << 3);

    for (int n = 0; n < NBATCH; ++n) {
        const int tb = n << 6;

        // 1. validate this batch's boundary (steady state: no spin)
        if (g > 0) {
            while (has_sent(qv, tb, lane)) qv = bload(colL, tb + lane);
        }

        // 2. counted wait: stage(n) (issued at end of batch n-2) has landed
        __builtin_amdgcn_sched_barrier(0);
        if (g > 0) asm volatile("s_waitcnt vmcnt(34)" ::: "memory");
        else       asm volatile("s_waitcnt vmcnt(33)" ::: "memory");
        __builtin_amdgcn_sched_barrier(0);

        // 3. prefetch next batch's boundary (validated next batch)
        float qvn = INFV;
        if (g > 0) qvn = bload(colL, tb + 64 + lane);

        // 4. chain: grouped LDS reads + 64-step register chain
        float2 rv[BATCH];
        #pragma unroll
        for (int s = 0; s < BATCH; ++s)
            rv[s] = *reinterpret_cast<const float2*>(
                (const char*)ring +
                ((caddr + (unsigned)(s * 512)) & (RINGB - 1)));

        float* obp = (lane == 63) ? &outbox[0] : &outdummy[lane];
        float pbc = INFV;
        #pragma unroll
        for (int s = 0; s < BATCH; ++s) {
            const float e0 = __expf(-rv[s].x);
            const float e1 = __expf(-rv[s].y);
            float bcur;
            if (g == 0)
                bcur = (n == 0 && s == 0) ? 0.f : INFV;   // (0,0) corner
            else
                bcur = __int_as_float(
                    __builtin_amdgcn_readlane(__float_as_int(qv), s));
            const float bpv = (g == 0) ? INFV : ((s == 0) ? bprevc : pbc);
            // chain: cndmask -> min3 -> add -> fmin -> add -> dpp
            const float L1 = lane0 ? bcur : l1s;   // c[r][col-1]
            const float L2 = lane0 ? bpv : l2s;    // c[r-1][col-1]
            const float m0 = fminf(fminf(L1, cur0), L2);
            const float c0 = e0 + m0;
            const float c1 = e1 + fminf(c0, fminf(cur0, cur1));
            *obp = c1;                 // lane63 -> outbox[s], rest -> dummy
            obp += ostep;
            const float sh = dpp_wave_shr1(c1);
            l2s = l1s; l1s = sh;
            cur0 = c0; cur1 = c1;
            pbc = bcur;
            if (s == 62) save = c1;    // final cell: n=64, s=62 (r=4095)
        }
        bprevc = pbc;
        caddr = (caddr + (unsigned)(BATCH * 512)) & (RINGB - 1);

        // 5. publish rows [tb-63, tb]: outbox -> one agent store per lane
        asm volatile("s_waitcnt lgkmcnt(0)" ::: "memory");
        {
            const float ob = outbox[lane];
            asm volatile("s_waitcnt lgkmcnt(0)" ::: "memory");
            __hip_atomic_store(colM + (tb - 63 + lane), __float_as_uint(ob),
                               __ATOMIC_RELAXED, __HIP_MEMORY_SCOPE_AGENT);
        }

        // 6. stage rows [tb+128, tb+192) (batch n+2), post-chain
        stageB(Dg, ring, tb + 128, lane);

        qv = qvn;
    }

    if (g == STRIPS - 1 && lane == 63) cost_out[0] = save;
}

// ---------------------------------------------------------------------------
// acc_grad[i,j] = d[i+1,j+1] + d[i+1,j] + d[i,j+1] - d[i,j],  d = exp(-exp(-D))
// (zero-padded bottom/right).
// ---------------------------------------------------------------------------
__device__ __forceinline__ float dfun(float x) { return __expf(-__expf(-x)); }

__global__ __launch_bounds__(256) void dtw_grad_kernel(const float* __restrict__ D,
                                                       float* __restrict__ G) {
    const int idx = blockIdx.x * 256 + threadIdx.x;
    const int i = idx >> 10;
    const int j = (idx & 1023) << 2;
    if (i >= NN) return;

    const float* row0 = D + (size_t)i * NN + j;
    const bool hasR = (i + 1) < NN;
    const bool hasC = (j + 4) < NN;

    const float4 r0 = *reinterpret_cast<const float4*>(row0);
    float4 r1 = make_float4(0.f, 0.f, 0.f, 0.f);
    if (hasR) r1 = *reinterpret_cast<const float4*>(row0 + NN);
    const float s0 = hasC ? row0[4] : 0.f;
    const float s1 = (hasR && hasC) ? row0[NN + 4] : 0.f;

    const float a0 = dfun(r0.x), a1 = dfun(r0.y), a2 = dfun(r0.z), a3 = dfun(r0.w);
    const float a4 = hasC ? dfun(s0) : 0.f;
    const float b0 = hasR ? dfun(r1.x) : 0.f;
    const float b1 = hasR ? dfun(r1.y) : 0.f;
    const float b2 = hasR ? dfun(r1.z) : 0.f;
    const float b3 = hasR ? dfun(r1.w) : 0.f;
    const float b4 = (hasR && hasC) ? dfun(s1) : 0.f;

    float* go = G + (size_t)i * NN + j;
    go[0] = b1 + b0 + a1 - a0;
    go[1] = b2 + b1 + a2 - a1;
    go[2] = b3 + b2 + a3 - a2;
    go[3] = b4 + b3 + a4 - a3;
}

// ---------------------------------------------------------------------------
extern "C" void kernel_launch(void* const* d_in, const int* in_sizes, int n_in,
                              void* d_out, int out_size, void* d_ws, size_t ws_size,
                              hipStream_t stream) {
    (void)in_sizes; (void)n_in; (void)out_size;
    const float* D = (const float*)d_in[0];
    float* out = (float*)d_out;

    const size_t colbytes = (size_t)STRIPS * COLPITCH * sizeof(unsigned);
    const int gblocks = (NN * (NN / 4)) / 256;

    // fallback: live inside the grad region (rewritten by the later grad
    // kernel, stream-ordered after the DP)
    unsigned* colbuf = (ws_size >= colbytes) ? (unsigned*)d_ws
                                             : (unsigned*)(out + 1);

    hipMemsetAsync(colbuf, 0xFF, colbytes, stream);
    dtw_dp<<<STRIPS, 64, 0, stream>>>(D, out, colbuf);
    dtw_grad_kernel<<<gblocks, 256, 0, stream>>>(D, out + 1);
}